// Round 8
// baseline (118.968 us; speedup 1.0000x reference)
//
#include <hip/hip_runtime.h>
#include <math.h>

#define NUM_GRAPHS 48
#define F 128
#define TM 32          // atoms per MLP tile
#define KC 32          // k-chunk staged in LDS
#define NCHUNK (F / KC)
#define R 8            // pair blocks per graph
#define NPB (NUM_GRAPHS * R)
#define CHUNK 512      // atoms staged per LDS chunk in pair kernel

__device__ __forceinline__ float softplus_f(float x) {
    return fmaxf(x, 0.0f) + log1pf(expf(-fabsf(x)));
}
__device__ __forceinline__ float silu_f(float x) {
    return x / (1.0f + expf(-x));
}

// LDS-staged tiled GEMM MLP. Block = (32-atom tile, one head).
// grid = (N/TM) * 2.  256 threads: thread (g2 = tid>>7, j = tid&127) computes
// hidden column j for 16 atoms of its half-tile. Per K-chunk, W[32k x 128j]
// (16 KB) and h0[32a x 32k] (4 KB) are staged into LDS with bulk coalesced
// float4 loads, register-pipelined so chunk c+1's global loads overlap chunk
// c's compute. Compute reads: weights via stride-1 ds_read_b32 (2-way, free),
// h0 via same-address ds_read_b128 broadcast (conflict-free).
__global__ __launch_bounds__(256) void mlp_kernel(
    const float* __restrict__ h0,
    const float* __restrict__ qW1, const float* __restrict__ qb1,
    const float* __restrict__ qW2,
    const float* __restrict__ vW1, const float* __restrict__ vb1,
    const float* __restrict__ vW2, const float* __restrict__ vb2,
    const int* __restrict__ batch, int* __restrict__ seg,
    float* __restrict__ q_raw, float* __restrict__ c6s, float* __restrict__ rv3,
    float* __restrict__ out, int N)
{
    __shared__ float ws[KC * F];        // 16 KB, [k][j]
    __shared__ float hs[TM * KC];       // 4 KB,  [a][k]
    __shared__ float red[4][16][2];

    const int tid  = threadIdx.x;
    const int head = blockIdx.x & 1;
    const int tile = blockIdx.x >> 1;
    const int a0   = tile * TM;

    if (blockIdx.x == 0) {   // segment boundaries of sorted batch + out init
        if (tid == 0) out[0] = 0.0f;
        for (int i = tid; i < N; i += 256) {
            int b = batch[i];
            int prev = (i == 0) ? -1 : batch[i - 1];
            for (int g = prev + 1; g <= b; ++g) seg[g] = i;
            if (i == N - 1) {
                for (int g = b + 1; g <= NUM_GRAPHS; ++g) seg[g] = N;
            }
        }
    }

    const float* __restrict__ W1 = head ? vW1 : qW1;
    const float* __restrict__ b1 = head ? vb1 : qb1;
    const float4* __restrict__ W14 = (const float4*)W1;

    const int j  = tid & 127;
    const int g2 = tid >> 7;

    float acc[16];
    const float bias = b1[j];
    #pragma unroll
    for (int a = 0; a < 16; ++a) acc[a] = bias;

    float4* ws4 = (float4*)ws;
    float4* hs4 = (float4*)hs;

    // ---- prefetch chunk 0 into registers ----
    float4 wreg[4];
    float4 hreg;
    {
        #pragma unroll
        for (int u = 0; u < 4; ++u)
            wreg[u] = W14[u * 256 + tid];            // chunk 0: first KC rows of W
        int a = tid >> 3, k4 = tid & 7;
        int row = a0 + a;
        hreg = make_float4(0.f, 0.f, 0.f, 0.f);
        if (row < N) hreg = ((const float4*)(h0 + (size_t)row * F))[k4];
    }

    for (int c = 0; c < NCHUNK; ++c) {
        __syncthreads();
        #pragma unroll
        for (int u = 0; u < 4; ++u) ws4[u * 256 + tid] = wreg[u];
        hs4[tid] = hreg;
        __syncthreads();

        if (c + 1 < NCHUNK) {   // issue next chunk's global loads now
            int cn = c + 1;
            #pragma unroll
            for (int u = 0; u < 4; ++u)
                wreg[u] = W14[cn * (KC * F / 4) + u * 256 + tid];
            int a = tid >> 3, k4 = tid & 7;
            int row = a0 + a;
            hreg = make_float4(0.f, 0.f, 0.f, 0.f);
            if (row < N) hreg = ((const float4*)(h0 + (size_t)row * F))[cn * (KC / 4) + k4];
        }

        #pragma unroll
        for (int k4 = 0; k4 < KC / 4; ++k4) {
            float w0 = ws[(k4 * 4 + 0) * F + j];
            float w1 = ws[(k4 * 4 + 1) * F + j];
            float w2 = ws[(k4 * 4 + 2) * F + j];
            float w3 = ws[(k4 * 4 + 3) * F + j];
            #pragma unroll
            for (int a = 0; a < 16; ++a) {
                float4 hv = hs4[(g2 * 16 + a) * (KC / 4) + k4];
                float t = acc[a];
                t = fmaf(hv.x, w0, t);
                t = fmaf(hv.y, w1, t);
                t = fmaf(hv.z, w2, t);
                t = fmaf(hv.w, w3, t);
                acc[a] = t;
            }
        }
    }

    // ---- second layer: reduce over j (butterfly within wave, pair via LDS) ----
    const int wave = tid >> 6;
    if (head == 0) {
        const float w2q = qW2[j];
        #pragma unroll
        for (int a = 0; a < 16; ++a) {
            float pq = silu_f(acc[a]) * w2q;
            #pragma unroll
            for (int d = 32; d >= 1; d >>= 1) pq += __shfl_xor(pq, d);
            if ((tid & 63) == 0) red[wave][a][0] = pq;
        }
        __syncthreads();
        if (tid < TM) {
            int gg = tid >> 4, a = tid & 15;
            int row = a0 + tid;
            if (row < N)
                q_raw[row] = red[2 * gg][a][0] + red[2 * gg + 1][a][0];
        }
    } else {
        const float w20 = vW2[2 * j];
        const float w21 = vW2[2 * j + 1];
        #pragma unroll
        for (int a = 0; a < 16; ++a) {
            float sv = silu_f(acc[a]);
            float p0 = sv * w20;
            float p1 = sv * w21;
            #pragma unroll
            for (int d = 32; d >= 1; d >>= 1) {
                p0 += __shfl_xor(p0, d);
                p1 += __shfl_xor(p1, d);
            }
            if ((tid & 63) == 0) { red[wave][a][0] = p0; red[wave][a][1] = p1; }
        }
        __syncthreads();
        if (tid < TM) {
            int gg = tid >> 4, a = tid & 15;
            int row = a0 + tid;
            if (row < N) {
                float p0 = red[2 * gg][a][0] + red[2 * gg + 1][a][0];
                float p1 = red[2 * gg][a][1] + red[2 * gg + 1][a][1];
                c6s[row] = sqrtf(softplus_f(p0 + vb2[0]));
                float r  = softplus_f(p1 + vb2[1]);
                rv3[row] = r * r * r;
            }
        }
    }
}

// 256 threads = 4 waves per block, R blocks per graph. Segment staged into
// LDS; inner loop is LDS+VALU only. Block partial -> one atomicAdd to out.
__global__ __launch_bounds__(256) void pair_kernel(
    const float* __restrict__ pos,
    const float* __restrict__ q_raw,
    const float* __restrict__ c6s, const float* __restrict__ rv3,
    const int* __restrict__ seg, const float* __restrict__ sigma_p,
    float* __restrict__ out)
{
    __shared__ float xs[CHUNK], ys[CHUNK], zs[CHUNK];
    __shared__ float qs[CHUNK], ss[CHUNK], r3[CHUNK];
    __shared__ float wred[4];

    const int g     = blockIdx.x / R;
    const int slice = blockIdx.x % R;
    const int tid   = threadIdx.x;
    const int wave  = tid >> 6;
    const int lane  = tid & 63;
    const int s0 = seg[g], s1 = seg[g + 1];
    const int n = s1 - s0;
    if (n <= 1) return;

    float acc = 0.0f;
    {
        // per-wave (redundant) mean of q over segment
        float ms = 0.f;
        for (int i = s0 + lane; i < s1; i += 64) ms += q_raw[i];
        #pragma unroll
        for (int d = 32; d >= 1; d >>= 1) ms += __shfl_xor(ms, d);
        const float mean = ms / (float)n;
        const float inv_ss = 1.0f / (1.41421356f * sigma_p[0]);
        const int wv = slice * 4 + wave;

        for (int c0 = s0; c0 < s1; c0 += CHUNK) {
            const int cn = min(CHUNK, s1 - c0);
            __syncthreads();
            for (int idx = tid; idx < cn; idx += 256) {
                int a = c0 + idx;
                xs[idx] = pos[3 * a + 0];
                ys[idx] = pos[3 * a + 1];
                zs[idx] = pos[3 * a + 2];
                qs[idx] = (q_raw[a] - mean) * (0.5f * 14.3996f);
                ss[idx] = c6s[a] * 0.5f;
                r3[idx] = rv3[a];
            }
            __syncthreads();

            for (int i = s0 + wv; i < s1; i += 4 * R) {
                float xi = pos[3 * i + 0], yi = pos[3 * i + 1], zi = pos[3 * i + 2];
                float qi = q_raw[i] - mean;
                float si = c6s[i];
                float ri = rv3[i];
                for (int jd = lane; jd < cn; jd += 64) {
                    if (c0 + jd == i) continue;
                    float dx = xi - xs[jd];
                    float dy = yi - ys[jd];
                    float dz = zi - zs[jd];
                    float d2 = fmaf(dx, dx, fmaf(dy, dy, dz * dz));
                    float dist = sqrtf(d2 + 1e-8f);
                    float e1 = qi * qs[jd] * erff(dist * inv_ss) / (dist + 1e-8f);
                    float damp = fmaf(d2 * d2, d2, fmaf(ri, r3[jd], 1e-8f));
                    float e2 = si * ss[jd] / damp;
                    acc += e1 - e2;
                }
            }
        }
    }
    #pragma unroll
    for (int d = 32; d >= 1; d >>= 1) acc += __shfl_xor(acc, d);
    if (lane == 0) wred[wave] = acc;
    __syncthreads();
    if (tid == 0) atomicAdd(out, wred[0] + wred[1] + wred[2] + wred[3]);
}

extern "C" void kernel_launch(void* const* d_in, const int* in_sizes, int n_in,
                              void* d_out, int out_size, void* d_ws, size_t ws_size,
                              hipStream_t stream) {
    const float* h0   = (const float*)d_in[0];
    // d_in[1] = h1 (unused on this path)
    const float* pos  = (const float*)d_in[2];
    const float* qW1  = (const float*)d_in[3];
    const float* qb1  = (const float*)d_in[4];
    const float* qW2  = (const float*)d_in[5];
    const float* sig  = (const float*)d_in[6];
    const float* vW1  = (const float*)d_in[7];
    const float* vb1  = (const float*)d_in[8];
    const float* vW2  = (const float*)d_in[9];
    const float* vb2  = (const float*)d_in[10];
    const int*  batch = (const int*)d_in[11];
    const int N = in_sizes[0] / F;   // 6144

    char* ws = (char*)d_ws;
    int*   seg   = (int*)ws;                 // 49 ints
    float* q_raw = (float*)(ws + 1024);      // N floats
    float* c6s   = q_raw + N;
    float* rv3   = c6s + N;
    float* out   = (float*)d_out;

    mlp_kernel<<<(N / TM) * 2, 256, 0, stream>>>(
        h0, qW1, qb1, qW2, vW1, vb1, vW2, vb2, batch, seg, q_raw, c6s, rv3, out, N);
    pair_kernel<<<NPB, 256, 0, stream>>>(pos, q_raw, c6s, rv3, seg, sig, out);
}